// Round 8
// baseline (643.337 us; speedup 1.0000x reference)
//
#include <hip/hip_runtime.h>
#include <hip/hip_bf16.h>
#include <stdint.h>

// Problem constants (B=4096, V=512, H=64)
#define BB 4096
#define VV 512
#define HH 64

typedef short bf16x8 __attribute__((ext_vector_type(8)));
typedef float floatx4 __attribute__((ext_vector_type(4)));
typedef unsigned short ushort8 __attribute__((ext_vector_type(8)));

typedef const __attribute__((address_space(1))) void g_void;
typedef __attribute__((address_space(3))) void l_void;

__device__ __forceinline__ void gload_lds16(const void* g, void* l) {
    __builtin_amdgcn_global_load_lds((g_void*)g, (l_void*)l, 16, 0, 0);
}

__device__ __forceinline__ unsigned short f2bf_rne(float f) {
    unsigned int u = __float_as_uint(f);
    u += 0x7FFFu + ((u >> 16) & 1u);   // round-to-nearest-even
    return (unsigned short)(u >> 16);
}

// ---------------------------------------------------------------- adj only
__global__ __launch_bounds__(256) void adj_kernel(const float* __restrict__ logits,
                                                  float* __restrict__ adj_out) {
    int idx = blockIdx.x * 256 + threadIdx.x;
    int v = idx >> 9, u = idx & (VV - 1);
    adj_out[idx] = (logits[idx] > 0.0f && v != u) ? 1.0f : 0.0f;
}

// ---------------------------------------------------------------- fused prep
// blocks [0, 1024): (i, v-half) pairs -- W1[i][v][h]*adj[v,i] -> bf16
//   W1t[i][h][v].  Double-buffered LDS tile, load(s+1) overlaps store(s).
// blocks [1024, 2048): adj output + X -> packed bf16 Xp (contiguous reads,
//   scattered fire-and-forget writes).
// Xp layout: chunk (rb,ks,mt,lane) holds
//   X[rb*64+mt*16+(lane&15)][ks*32+(lane>>4)*8 ..+7].
__global__ __launch_bounds__(256) void prep_fused_kernel(
        const float* __restrict__ X, const float* __restrict__ logits,
        const float* __restrict__ W1, float* __restrict__ adj_out,
        unsigned short* __restrict__ Xp, unsigned short* __restrict__ W1t) {
    __shared__ float tile[2][64][65];   // double buffer; stride 65: conflict-free
    __shared__ float maskv[256];
    int bx = blockIdx.x;
    int t  = threadIdx.x;
    if (bx < 1024) {
        int i  = bx >> 1;
        int v0 = (bx & 1) << 8;         // v-half base: 0 or 256
        {
            int v = v0 + t;
            maskv[t] = (logits[(size_t)v * VV + i] > 0.0f && v != i) ? 1.0f : 0.0f;
        }
        const float4* src4 = (const float4*)(W1 + ((size_t)i * VV + v0) * HH);
        unsigned short* dst0 = W1t + (size_t)i * (HH * VV) + v0;

        // load sub-tile s (64 v-rows of 64 h) into buffer b
        auto load = [&](int s, int b) {
            #pragma unroll
            for (int jj = 0; jj < 4; ++jj) {
                int c  = jj * 256 + t;         // float4 index in [0, 1024)
                int vr = c >> 4, h4 = c & 15;
                float4 w = src4[s * 1024 + c];
                tile[b][vr][h4 * 4 + 0] = w.x;
                tile[b][vr][h4 * 4 + 1] = w.y;
                tile[b][vr][h4 * 4 + 2] = w.z;
                tile[b][vr][h4 * 4 + 3] = w.w;
            }
        };
        // transpose-store sub-tile s from buffer b (masked, bf16)
        auto store = [&](int s, int b) {
            #pragma unroll
            for (int j = 0; j < 2; ++j) {
                int c = j * 256 + t;
                int h = c >> 3;
                int vr0 = (c & 7) * 8;
                ushort8 o;
                #pragma unroll
                for (int r = 0; r < 8; ++r)
                    o[r] = f2bf_rne(tile[b][vr0 + r][h] * maskv[s * 64 + vr0 + r]);
                *(ushort8*)&dst0[(size_t)h * VV + s * 64 + vr0] = o;
            }
        };

        load(0, 0);
        __syncthreads();                 // tile0 + maskv ready
        #pragma unroll
        for (int s = 0; s < 4; ++s) {
            if (s < 3) load(s + 1, (s + 1) & 1);   // overlaps store(s)
            store(s, s & 1);
            __syncthreads();             // buffer handoff
        }
    } else {
        int idx = (bx - 1024) * 256 + t;           // [0, 262144)
        {   // adj: sigmoid(x) > 0.5  <=>  x > 0 ; zero diagonal
            int v = idx >> 9, u = idx & (VV - 1);
            adj_out[idx] = (logits[idx] > 0.0f && v != u) ? 1.0f : 0.0f;
        }
        {   // X pack: contiguous 32 B read per thread, scattered 16 B write
            int row = idx >> 6;
            int k0  = (idx & 63) << 3;             // 8-float chunk within row
            const float4* s4 = (const float4*)(X + (size_t)row * VV + k0);
            float4 a = s4[0], b = s4[1];
            ushort8 o;
            o[0] = f2bf_rne(a.x); o[1] = f2bf_rne(a.y);
            o[2] = f2bf_rne(a.z); o[3] = f2bf_rne(a.w);
            o[4] = f2bf_rne(b.x); o[5] = f2bf_rne(b.y);
            o[6] = f2bf_rne(b.z); o[7] = f2bf_rne(b.w);
            int rb = row >> 6, mt = (row >> 4) & 3, lnr = row & 15;
            int ks = k0 >> 5, quad = (k0 >> 3) & 3;
            size_t chunk = (((size_t)(rb * 16 + ks) * 4 + mt) << 6) + quad * 16 + lnr;
            *(ushort8*)(Xp + chunk * 8) = o;
        }
    }
}

// ---------------------------------------------------------------- main GEMM
// B-STATIONARY persistent blocks. Ledger: R3/R5 equilibrium (147.7 us) has
// no pipe >40%; its residual costs are (a) 3 full drain barriers per block
// x 16 generations, (b) W1t staged 8x (256 MB repeated B traffic). This
// version removes BOTH without touching the proven inner k-step:
//   grid = 256 blocks (1/CU), 512 thr (8 waves = SAME 8 waves/CU as R3's
//   2x4-wave blocks). Block owns one i-pair; stages full-K B for both i's
//   ONCE (128 KB LDS), single __syncthreads, then each wave sweeps its
//   512 rows of Xp (8 chunks x 16 k-steps) with depth-1 register prefetch.
//   ZERO barriers in steady state (B is read-only); B fetched once
//   (32 MB total); no generational cold-starts; uniform grid = no tail.
// Same MFMA order per output element as R3 -> bit-identical numerics.
// LDS 128K B + 4K Po = 132 KB < 160. Per-wave register body identical to
// R3 (acc 2x4x4, af[2][4], bq[2][2][4]) -> no spill at (512,2).
// Falsifier (pre-committed): dur >= 148 us => A-latency-bound, structural;
// restore R5 and declare plateau.
__global__ __launch_bounds__(512, 2) void dag_gemm_kernel(
        const unsigned short* __restrict__ Xp,    // packed A frags
        const unsigned short* __restrict__ W1t,   // [V][H][V] bf16 (masked, B^T)
        const float* __restrict__ b1,             // [V][H]
        const float* __restrict__ W2,             // [V][H]
        const float* __restrict__ b2,             // [V]
        float* __restrict__ out)                  // [B][V] final output
{
    // Ws[ii]: [64 h][64 slots of 16B] = 64 KB per i (full K=512)
    __shared__ __align__(16) unsigned short Ws[2][32768];  // 128 KB
    __shared__ float Po[2][512];                           // per-wave gather

    const int t    = threadIdx.x;
    const int wave = t >> 6;
    const int lane = t & 63;
    const int ln   = lane & 15;
    const int quad = lane >> 4;

    const int i0 = blockIdx.x << 1;       // 256 blocks, one i-pair each

    // B-frag fetch: pos = full-K 16B chunk index [0,64) of row h=nt*16+ln.
    // XOR swizzle on low 3 bits, matched by pre-swizzled staging source
    // (ln&7 == h&7 for h = nt*16+ln).
    auto ldb = [&](int ii, int pos, int nt) -> bf16x8 {
        return *(const bf16x8*)&Ws[ii][(nt * 16 + ln) * 512 + ((pos ^ (ln & 7)) * 8)];
    };

    // ---- A prefetch for wave's first chunk, ks=0 (oldest in vmem queue)
    bf16x8 af[2][4];
    const unsigned short* ab0 =
        Xp + (size_t)(wave * 8) * (64 * VV) + lane * 8;
    #pragma unroll
    for (int mt = 0; mt < 4; ++mt)
        af[0][mt] = *(const bf16x8*)(ab0 + mt * 512);

    // ---- stage full-K W1t for both i's: 8192 chunks x 16 B, ONCE.
    // dst = c*16 (wave-uniform base + lane*16: m104-safe); source slot
    // pre-swizzled s2 ^ (h&7) (involution matches ldb's read XOR).
    {
        const unsigned short* wb = W1t + (size_t)i0 * (HH * VV);
        #pragma unroll
        for (int j = 0; j < 16; ++j) {
            int c  = j * 512 + t;         // [0, 8192)
            int ii = c >> 12, h = (c >> 6) & 63, s2 = c & 63;
            gload_lds16(wb + (size_t)ii * (HH * VV) + (size_t)h * VV
                           + (size_t)(s2 ^ (h & 7)) * 8,
                        (char*)Ws + c * 16);
        }
    }
    __syncthreads();   // THE ONLY BARRIER: B staged + af[0] complete

    // ---- epilogue constants (one i-pair for the whole kernel)
    float b1v[2][4], w2v[2][4], b2i[2];
    #pragma unroll
    for (int ii = 0; ii < 2; ++ii) {
        #pragma unroll
        for (int nt = 0; nt < 4; ++nt) {
            b1v[ii][nt] = b1[(i0 + ii) * HH + nt * 16 + ln];
            w2v[ii][nt] = W2[(i0 + ii) * HH + nt * 16 + ln];
        }
        b2i[ii] = b2[i0 + ii];
    }

    bf16x8 bq[2][2][4];                   // [step parity][ii][nt]
    #pragma unroll
    for (int ii = 0; ii < 2; ++ii)
        #pragma unroll
        for (int nt = 0; nt < 4; ++nt)
            bq[0][ii][nt] = ldb(ii, quad, nt);

    // ---- steady state: 8 chunks of 64 rows, NO barriers.
    #pragma unroll 1
    for (int c = 0; c < 8; ++c) {
        const unsigned short* ab =
            Xp + (size_t)(wave * 8 + c) * (64 * VV) + lane * 8;
        const unsigned short* abn = ab + 64 * VV;   // next chunk

        floatx4 acc[2][4][4];
        #pragma unroll
        for (int ii = 0; ii < 2; ++ii)
            #pragma unroll
            for (int a = 0; a < 4; ++a)
                #pragma unroll
                for (int b = 0; b < 4; ++b)
                    acc[ii][a][b] = (floatx4){0.f, 0.f, 0.f, 0.f};

        #pragma unroll
        for (int kk = 0; kk < 16; ++kk) {
            // A prefetch for next step (crosses chunk boundary at kk=15)
            if (kk < 15) {
                #pragma unroll
                for (int mt = 0; mt < 4; ++mt)
                    af[(kk + 1) & 1][mt] =
                        *(const bf16x8*)(ab + ((kk + 1) * 4 + mt) * 512);
            } else if (c < 7) {
                #pragma unroll
                for (int mt = 0; mt < 4; ++mt)
                    af[0][mt] = *(const bf16x8*)(abn + mt * 512);
            }
            // B prefetch for next step (wraps to pos=quad at chunk end;
            // B LDS is read-only so no sync needed)
            if (kk < 15) {
                #pragma unroll
                for (int ii = 0; ii < 2; ++ii)
                    #pragma unroll
                    for (int nt = 0; nt < 4; ++nt)
                        bq[(kk + 1) & 1][ii][nt] = ldb(ii, (kk + 1) * 4 + quad, nt);
            } else if (c < 7) {
                #pragma unroll
                for (int ii = 0; ii < 2; ++ii)
                    #pragma unroll
                    for (int nt = 0; nt < 4; ++nt)
                        bq[0][ii][nt] = ldb(ii, quad, nt);
            }
            #pragma unroll
            for (int ii = 0; ii < 2; ++ii)
                #pragma unroll
                for (int mt = 0; mt < 4; ++mt)
                    #pragma unroll
                    for (int nt = 0; nt < 4; ++nt)
                        acc[ii][mt][nt] = __builtin_amdgcn_mfma_f32_16x16x32_bf16(
                            af[kk & 1][mt], bq[kk & 1][ii][nt], acc[ii][mt][nt], 0, 0, 0);
        }

        // ---- fused epilogue for this 64-row chunk: relu(acc+b1).W2 + b2.
        // Po gather is strictly intra-wave -> no barrier; overlaps the
        // already-issued next-chunk prefetches.
        #pragma unroll
        for (int ii = 0; ii < 2; ++ii) {
            #pragma unroll
            for (int mt = 0; mt < 4; ++mt) {
                #pragma unroll
                for (int r = 0; r < 4; ++r) {
                    float p = 0.f;
                    #pragma unroll
                    for (int nt = 0; nt < 4; ++nt) {
                        float hv = acc[ii][mt][nt][r] + b1v[ii][nt];   // row=quad*4+r, col=nt*16+ln
                        hv = hv > 0.f ? hv : 0.f;
                        p += hv * w2v[ii][nt];
                    }
                    p += __shfl_xor(p, 8);
                    p += __shfl_xor(p, 4);
                    p += __shfl_xor(p, 2);
                    p += __shfl_xor(p, 1);
                    if (ln == 0)
                        Po[ii][wave * 64 + mt * 16 + quad * 4 + r] = p + b2i[ii];
                }
            }
        }
        const int row = (wave * 8 + c) * 64 + lane;
        out[(size_t)row * VV + i0]     = Po[0][wave * 64 + lane];
        out[(size_t)row * VV + i0 + 1] = Po[1][wave * 64 + lane];
    }
}

// ----------------------------- fallback (no workspace): fp32 vector path
__global__ __launch_bounds__(256) void fallback_kernel(
        const float* __restrict__ X, const float* __restrict__ logits,
        const float* __restrict__ W1, const float* __restrict__ b1,
        const float* __restrict__ W2, const float* __restrict__ b2,
        float* __restrict__ out) {
    __shared__ float Wc[128][64];
    int i   = blockIdx.x & (VV - 1);
    int row = (blockIdx.x >> 9) * 256 + threadIdx.x;
    float acc[64];
    #pragma unroll
    for (int h = 0; h < 64; ++h) acc[h] = 0.f;
    for (int v0 = 0; v0 < VV; v0 += 128) {
        __syncthreads();
        for (int j = 0; j < 32; ++j) {
            int idx = j * 256 + threadIdx.x;
            int vr = idx >> 6, h = idx & 63;
            int v = v0 + vr;
            float m = (logits[(size_t)v * VV + i] > 0.f && v != i) ? 1.f : 0.f;
            Wc[vr][h] = W1[((size_t)i * VV + v) * HH + h] * m;
        }
        __syncthreads();
        for (int vr = 0; vr < 128; ++vr) {
            float xv = X[(size_t)row * VV + v0 + vr];
            #pragma unroll
            for (int h = 0; h < 64; ++h) acc[h] += xv * Wc[vr][h];
        }
    }
    float p = b2[i];
    #pragma unroll
    for (int h = 0; h < 64; ++h) {
        float hv = acc[h] + b1[i * HH + h];
        p += (hv > 0.f ? hv : 0.f) * W2[i * HH + h];
    }
    out[(size_t)row * VV + i] = p;
}

extern "C" void kernel_launch(void* const* d_in, const int* in_sizes, int n_in,
                              void* d_out, int out_size, void* d_ws, size_t ws_size,
                              hipStream_t stream) {
    const float* X      = (const float*)d_in[0];
    const float* logits = (const float*)d_in[1];
    const float* W1     = (const float*)d_in[2];
    const float* b1     = (const float*)d_in[3];
    const float* W2     = (const float*)d_in[4];
    const float* b2     = (const float*)d_in[5];

    float* out     = (float*)d_out;                       // reconstructed [B][V]
    float* adj_out = out + (size_t)BB * VV;               // adj [V][V]

    const size_t xp_bytes  = (size_t)BB * VV * 2;         // 4 MB
    const size_t w1t_bytes = (size_t)VV * HH * VV * 2;    // 32 MB
    const size_t need = xp_bytes + w1t_bytes;

    if (ws_size >= need) {
        unsigned short* Xp  = (unsigned short*)d_ws;
        unsigned short* W1t = (unsigned short*)((char*)d_ws + xp_bytes);
        hipLaunchKernelGGL(prep_fused_kernel, dim3(2048), dim3(256), 0, stream,
                           X, logits, W1, adj_out, Xp, W1t);
        hipLaunchKernelGGL(dag_gemm_kernel, dim3(256), dim3(512), 0, stream,
                           Xp, W1t, b1, W2, b2, out);
    } else {
        hipLaunchKernelGGL(adj_kernel, dim3((VV * VV) / 256), dim3(256), 0, stream,
                           logits, adj_out);
        hipLaunchKernelGGL(fallback_kernel, dim3(VV * (BB / 256)), dim3(256), 0, stream,
                           X, logits, W1, b1, W2, b2, out);
    }
}

// Round 9
// 239.228 us; speedup vs baseline: 2.6892x; 2.6892x over previous
//
#include <hip/hip_runtime.h>
#include <hip/hip_bf16.h>
#include <stdint.h>

// Problem constants (B=4096, V=512, H=64)
#define BB 4096
#define VV 512
#define HH 64

typedef short bf16x8 __attribute__((ext_vector_type(8)));
typedef float floatx4 __attribute__((ext_vector_type(4)));
typedef unsigned short ushort8 __attribute__((ext_vector_type(8)));

typedef const __attribute__((address_space(1))) void g_void;
typedef __attribute__((address_space(3))) void l_void;

__device__ __forceinline__ void gload_lds16(const void* g, void* l) {
    __builtin_amdgcn_global_load_lds((g_void*)g, (l_void*)l, 16, 0, 0);
}

__device__ __forceinline__ unsigned short f2bf_rne(float f) {
    unsigned int u = __float_as_uint(f);
    u += 0x7FFFu + ((u >> 16) & 1u);   // round-to-nearest-even
    return (unsigned short)(u >> 16);
}

// ---------------------------------------------------------------- adj only
__global__ __launch_bounds__(256) void adj_kernel(const float* __restrict__ logits,
                                                  float* __restrict__ adj_out) {
    int idx = blockIdx.x * 256 + threadIdx.x;
    int v = idx >> 9, u = idx & (VV - 1);
    adj_out[idx] = (logits[idx] > 0.0f && v != u) ? 1.0f : 0.0f;
}

// ---------------------------------------------------------------- fused prep
// blocks [0, 1024): (i, v-half) pairs -- W1[i][v][h]*adj[v,i] -> bf16
//   W1t[i][h][v].  Double-buffered LDS tile, load(s+1) overlaps store(s).
// blocks [1024, 2048): adj output + X -> packed bf16 Xp (contiguous reads,
//   scattered fire-and-forget writes).
// Xp layout: chunk (rb,ks,mt,lane) holds
//   X[rb*64+mt*16+(lane&15)][ks*32+(lane>>4)*8 ..+7].
__global__ __launch_bounds__(256) void prep_fused_kernel(
        const float* __restrict__ X, const float* __restrict__ logits,
        const float* __restrict__ W1, float* __restrict__ adj_out,
        unsigned short* __restrict__ Xp, unsigned short* __restrict__ W1t) {
    __shared__ float tile[2][64][65];   // double buffer; stride 65: conflict-free
    __shared__ float maskv[256];
    int bx = blockIdx.x;
    int t  = threadIdx.x;
    if (bx < 1024) {
        int i  = bx >> 1;
        int v0 = (bx & 1) << 8;         // v-half base: 0 or 256
        {
            int v = v0 + t;
            maskv[t] = (logits[(size_t)v * VV + i] > 0.0f && v != i) ? 1.0f : 0.0f;
        }
        const float4* src4 = (const float4*)(W1 + ((size_t)i * VV + v0) * HH);
        unsigned short* dst0 = W1t + (size_t)i * (HH * VV) + v0;

        // load sub-tile s (64 v-rows of 64 h) into buffer b
        auto load = [&](int s, int b) {
            #pragma unroll
            for (int jj = 0; jj < 4; ++jj) {
                int c  = jj * 256 + t;         // float4 index in [0, 1024)
                int vr = c >> 4, h4 = c & 15;
                float4 w = src4[s * 1024 + c];
                tile[b][vr][h4 * 4 + 0] = w.x;
                tile[b][vr][h4 * 4 + 1] = w.y;
                tile[b][vr][h4 * 4 + 2] = w.z;
                tile[b][vr][h4 * 4 + 3] = w.w;
            }
        };
        // transpose-store sub-tile s from buffer b (masked, bf16)
        auto store = [&](int s, int b) {
            #pragma unroll
            for (int j = 0; j < 2; ++j) {
                int c = j * 256 + t;
                int h = c >> 3;
                int vr0 = (c & 7) * 8;
                ushort8 o;
                #pragma unroll
                for (int r = 0; r < 8; ++r)
                    o[r] = f2bf_rne(tile[b][vr0 + r][h] * maskv[s * 64 + vr0 + r]);
                *(ushort8*)&dst0[(size_t)h * VV + s * 64 + vr0] = o;
            }
        };

        load(0, 0);
        __syncthreads();                 // tile0 + maskv ready
        #pragma unroll
        for (int s = 0; s < 4; ++s) {
            if (s < 3) load(s + 1, (s + 1) & 1);   // overlaps store(s)
            store(s, s & 1);
            __syncthreads();             // buffer handoff
        }
    } else {
        int idx = (bx - 1024) * 256 + t;           // [0, 262144)
        {   // adj: sigmoid(x) > 0.5  <=>  x > 0 ; zero diagonal
            int v = idx >> 9, u = idx & (VV - 1);
            adj_out[idx] = (logits[idx] > 0.0f && v != u) ? 1.0f : 0.0f;
        }
        {   // X pack: contiguous 32 B read per thread, scattered 16 B write
            int row = idx >> 6;
            int k0  = (idx & 63) << 3;             // 8-float chunk within row
            const float4* s4 = (const float4*)(X + (size_t)row * VV + k0);
            float4 a = s4[0], b = s4[1];
            ushort8 o;
            o[0] = f2bf_rne(a.x); o[1] = f2bf_rne(a.y);
            o[2] = f2bf_rne(a.z); o[3] = f2bf_rne(a.w);
            o[4] = f2bf_rne(b.x); o[5] = f2bf_rne(b.y);
            o[6] = f2bf_rne(b.z); o[7] = f2bf_rne(b.w);
            int rb = row >> 6, mt = (row >> 4) & 3, lnr = row & 15;
            int ks = k0 >> 5, quad = (k0 >> 3) & 3;
            size_t chunk = (((size_t)(rb * 16 + ks) * 4 + mt) << 6) + quad * 16 + lnr;
            *(ushort8*)(Xp + chunk * 8) = o;
        }
    }
}

// ---------------------------------------------------------------- main GEMM
// Best-measured configuration, restored verbatim (R3/R5/R7: 147.6-151.5 us).
// Session ledger: 8-phase port (R1, -23us), XCD remap (R2, FETCH +46%),
// counted-vmcnt ring (R4, -5us), nt + JIT-bq (R6, -33us), B-stationary
// persistent blocks (R8, -400us: each block streaming all of Xp destroyed
// A L2 locality, FETCH 134MB -> 1.16GB, MfmaUtil 10%). Only IFUSE=2 won.
// The 16-block row-chunk co-scheduling IS the A-locality mechanism; the
// two-drain schedule with 2 blocks/CU mutually covering barriers is the
// measured equilibrium (A-load-latency-bound; no pipe >40%).
__global__ __launch_bounds__(256, 2) void dag_gemm_kernel(
        const unsigned short* __restrict__ Xp,    // packed A frags
        const unsigned short* __restrict__ W1t,   // [V][H][V] bf16 (masked, B^T)
        const float* __restrict__ b1,             // [V][H]
        const float* __restrict__ W2,             // [V][H]
        const float* __restrict__ b2,             // [V]
        float* __restrict__ out)                  // [B][V] final output
{
    __shared__ __align__(16) unsigned short Ws[2][16384];  // 64 KB: [i][h][s2]
    __shared__ float Po[2][256];                           // epilogue gather

    const int t    = threadIdx.x;
    const int wave = t >> 6;
    const int lane = t & 63;
    const int ln   = lane & 15;
    const int quad = lane >> 4;

    const int bx   = blockIdx.x;          // 4096 blocks, i-pair-major
    const int i0   = (bx >> 4) << 1;      // 16 consecutive blocks share i-pair
    const int row0 = (bx & 15) << 8;

    // B-frag fetch: pos = in-half chunk (k/8 units, [0,32)) of row h=nt*16+ln
    auto ldb = [&](int ii, int pos, int nt) -> bf16x8 {
        return *(const bf16x8*)&Ws[ii][(nt * 16 + ln) * 256 + ((pos ^ (ln & 7)) * 8)];
    };

    // wave's packed A stream: 64 KB contiguous, frag(ks,mt) at +(ks*4+mt)*512
    const unsigned short* abase =
        Xp + (size_t)((row0 >> 6) + wave) * (64 * VV) + lane * 8;

    // ---- A prefetch for step 0 (oldest in vmem queue)
    bf16x8 af[2][4];
    #pragma unroll
    for (int mt = 0; mt < 4; ++mt)
        af[0][mt] = *(const bf16x8*)(abase + mt * 512);

    // ---- stage W1t k-half (32 KB per i): lds addr = c*16 (lane-contiguous)
    const unsigned short* wb0 = W1t + (size_t)i0 * (HH * VV);
    const unsigned short* wb1 = W1t + (size_t)(i0 + 1) * (HH * VV);
    auto stage = [&](int kb) {            // kb = 0 (half0) or 32 (half1), in k/8 units
        #pragma unroll
        for (int j = 0; j < 8; ++j) {
            int c = j * 256 + t;          // [0, 2048)
            int h = c >> 5, s2 = c & 31;
            size_t off = (size_t)h * VV + (size_t)(kb + (s2 ^ (h & 7))) * 8;
            gload_lds16(wb0 + off, (char*)&Ws[0][0] + c * 16);
            gload_lds16(wb1 + off, (char*)&Ws[1][0] + c * 16);
        }
    };
    stage(0);
    __syncthreads();   // drains: half0 staged (both i) + af[0] complete

    floatx4 acc[2][4][4];
    #pragma unroll
    for (int ii = 0; ii < 2; ++ii)
        #pragma unroll
        for (int a = 0; a < 4; ++a)
            #pragma unroll
            for (int b = 0; b < 4; ++b)
                acc[ii][a][b] = (floatx4){0.f, 0.f, 0.f, 0.f};

    bf16x8 bq[2][2][4];                   // [step parity][ii][nt]
    #pragma unroll
    for (int ii = 0; ii < 2; ++ii)
        #pragma unroll
        for (int nt = 0; nt < 4; ++nt)
            bq[0][ii][nt] = ldb(ii, quad, nt);

    // ---- K-steps 0..7 (k in [0,256): half0)
    #pragma unroll
    for (int kk = 0; kk < 8; ++kk) {
        #pragma unroll
        for (int mt = 0; mt < 4; ++mt)     // A prefetch for step kk+1
            af[(kk + 1) & 1][mt] =
                *(const bf16x8*)(abase + ((kk + 1) * 4 + mt) * 512);
        if (kk < 7) {                      // B prefetch for step kk+1 (half0)
            #pragma unroll
            for (int ii = 0; ii < 2; ++ii)
                #pragma unroll
                for (int nt = 0; nt < 4; ++nt)
                    bq[(kk + 1) & 1][ii][nt] = ldb(ii, (kk + 1) * 4 + quad, nt);
        }
        #pragma unroll
        for (int ii = 0; ii < 2; ++ii)
            #pragma unroll
            for (int mt = 0; mt < 4; ++mt)
                #pragma unroll
                for (int nt = 0; nt < 4; ++nt)
                    acc[ii][mt][nt] = __builtin_amdgcn_mfma_f32_16x16x32_bf16(
                        af[kk & 1][mt], bq[kk & 1][ii][nt], acc[ii][mt][nt], 0, 0, 0);
    }

    __syncthreads();   // all waves done READING half0 (both i)

    // ---- re-stage half1 (k in [256,512)) into the SAME buffers
    stage(32);
    __syncthreads();   // drains half1 (covered by the other resident block)

    // B frags for step 8 (pos 0 of new half)
    #pragma unroll
    for (int ii = 0; ii < 2; ++ii)
        #pragma unroll
        for (int nt = 0; nt < 4; ++nt)
            bq[0][ii][nt] = ldb(ii, quad, nt);

    // ---- K-steps 8..15 (k in [256,512): half1)
    #pragma unroll
    for (int kk = 8; kk < 16; ++kk) {
        if (kk < 15) {
            #pragma unroll
            for (int mt = 0; mt < 4; ++mt)
                af[(kk + 1) & 1][mt] =
                    *(const bf16x8*)(abase + ((kk + 1) * 4 + mt) * 512);
            #pragma unroll
            for (int ii = 0; ii < 2; ++ii)
                #pragma unroll
                for (int nt = 0; nt < 4; ++nt)
                    bq[(kk + 1) & 1][ii][nt] = ldb(ii, ((kk + 1) - 8) * 4 + quad, nt);
        }
        #pragma unroll
        for (int ii = 0; ii < 2; ++ii)
            #pragma unroll
            for (int mt = 0; mt < 4; ++mt)
                #pragma unroll
                for (int nt = 0; nt < 4; ++nt)
                    acc[ii][mt][nt] = __builtin_amdgcn_mfma_f32_16x16x32_bf16(
                        af[kk & 1][mt], bq[kk & 1][ii][nt], acc[ii][mt][nt], 0, 0, 0);
    }

    // ---- fused epilogue: relu(acc + b1) . W2 + b2, fp32; Po gather is
    //      strictly intra-wave -> no barrier needed before the store.
    float b1v[2][4], w2v[2][4], b2i[2];
    #pragma unroll
    for (int ii = 0; ii < 2; ++ii) {
        #pragma unroll
        for (int nt = 0; nt < 4; ++nt) {
            b1v[ii][nt] = b1[(i0 + ii) * HH + nt * 16 + ln];
            w2v[ii][nt] = W2[(i0 + ii) * HH + nt * 16 + ln];
        }
        b2i[ii] = b2[i0 + ii];
    }
    #pragma unroll
    for (int ii = 0; ii < 2; ++ii) {
        #pragma unroll
        for (int mt = 0; mt < 4; ++mt) {
            #pragma unroll
            for (int r = 0; r < 4; ++r) {
                float p = 0.f;
                #pragma unroll
                for (int nt = 0; nt < 4; ++nt) {
                    float hv = acc[ii][mt][nt][r] + b1v[ii][nt];   // row=quad*4+r, col=nt*16+ln
                    hv = hv > 0.f ? hv : 0.f;
                    p += hv * w2v[ii][nt];
                }
                p += __shfl_xor(p, 8);
                p += __shfl_xor(p, 4);
                p += __shfl_xor(p, 2);
                p += __shfl_xor(p, 1);
                if (ln == 0)
                    Po[ii][wave * 64 + mt * 16 + quad * 4 + r] = p + b2i[ii];
            }
        }
    }
    // direct transposed store: two instrs/lane; writers of each 64 B out
    // line are bx-stride-16 time-adjacent blocks -> L2 write-merges
    // (WRITE_SIZE measured 8.2 MB = no amplification).
    const int row = row0 + wave * 64 + lane;
    out[(size_t)row * VV + i0]     = Po[0][wave * 64 + lane];
    out[(size_t)row * VV + i0 + 1] = Po[1][wave * 64 + lane];
}

// ----------------------------- fallback (no workspace): fp32 vector path
__global__ __launch_bounds__(256) void fallback_kernel(
        const float* __restrict__ X, const float* __restrict__ logits,
        const float* __restrict__ W1, const float* __restrict__ b1,
        const float* __restrict__ W2, const float* __restrict__ b2,
        float* __restrict__ out) {
    __shared__ float Wc[128][64];
    int i   = blockIdx.x & (VV - 1);
    int row = (blockIdx.x >> 9) * 256 + threadIdx.x;
    float acc[64];
    #pragma unroll
    for (int h = 0; h < 64; ++h) acc[h] = 0.f;
    for (int v0 = 0; v0 < VV; v0 += 128) {
        __syncthreads();
        for (int j = 0; j < 32; ++j) {
            int idx = j * 256 + threadIdx.x;
            int vr = idx >> 6, h = idx & 63;
            int v = v0 + vr;
            float m = (logits[(size_t)v * VV + i] > 0.f && v != i) ? 1.f : 0.f;
            Wc[vr][h] = W1[((size_t)i * VV + v) * HH + h] * m;
        }
        __syncthreads();
        for (int vr = 0; vr < 128; ++vr) {
            float xv = X[(size_t)row * VV + v0 + vr];
            #pragma unroll
            for (int h = 0; h < 64; ++h) acc[h] += xv * Wc[vr][h];
        }
    }
    float p = b2[i];
    #pragma unroll
    for (int h = 0; h < 64; ++h) {
        float hv = acc[h] + b1[i * HH + h];
        p += (hv > 0.f ? hv : 0.f) * W2[i * HH + h];
    }
    out[(size_t)row * VV + i] = p;
}

extern "C" void kernel_launch(void* const* d_in, const int* in_sizes, int n_in,
                              void* d_out, int out_size, void* d_ws, size_t ws_size,
                              hipStream_t stream) {
    const float* X      = (const float*)d_in[0];
    const float* logits = (const float*)d_in[1];
    const float* W1     = (const float*)d_in[2];
    const float* b1     = (const float*)d_in[3];
    const float* W2     = (const float*)d_in[4];
    const float* b2     = (const float*)d_in[5];

    float* out     = (float*)d_out;                       // reconstructed [B][V]
    float* adj_out = out + (size_t)BB * VV;               // adj [V][V]

    const size_t xp_bytes  = (size_t)BB * VV * 2;         // 4 MB
    const size_t w1t_bytes = (size_t)VV * HH * VV * 2;    // 32 MB
    const size_t need = xp_bytes + w1t_bytes;

    if (ws_size >= need) {
        unsigned short* Xp  = (unsigned short*)d_ws;
        unsigned short* W1t = (unsigned short*)((char*)d_ws + xp_bytes);
        hipLaunchKernelGGL(prep_fused_kernel, dim3(2048), dim3(256), 0, stream,
                           X, logits, W1, adj_out, Xp, W1t);
        hipLaunchKernelGGL(dag_gemm_kernel, dim3(4096), dim3(256), 0, stream,
                           Xp, W1t, b1, W2, b2, out);
    } else {
        hipLaunchKernelGGL(adj_kernel, dim3((VV * VV) / 256), dim3(256), 0, stream,
                           logits, adj_out);
        hipLaunchKernelGGL(fallback_kernel, dim3(VV * (BB / 256)), dim3(256), 0, stream,
                           X, logits, W1, b1, W2, b2, out);
    }
}